// Round 1
// baseline (102.554 us; speedup 1.0000x reference)
//
#include <hip/hip_runtime.h>

// LDDMM variational evolve: B=1, N=8192, D=3, fp32.
// dmom_i = 2*GAMMA * sum_j K_ij * <p_i,p_j> * (x_i - x_j)
// dx_i   = sum_j K_ij * p_j
// K_ij = exp(-GAMMA * |x_i - x_j|^2), GAMMA = 100.
//
// Strategy: j-loop split across blockIdx.y segments (grid 32x32 = 1024 blocks,
// ~4/CU). Each block stages a 256-point j-tile (x,p) into LDS; each thread owns
// one i and accumulates 7 partials; partials combined via fp32 atomicAdd into
// d_out (zeroed by a memset node first — d_out is poisoned before every call).

#define TPB 256
#define GAMMA_F 100.0f

__global__ __launch_bounds__(TPB) void lddmm_evolve_kernel(
    const float* __restrict__ mom,   // [N*3]
    const float* __restrict__ xpt,   // [N*3]
    float* __restrict__ out,         // [6*N]: dmom [3N] then dx [3N]
    int N) {
  const int i    = blockIdx.x * TPB + threadIdx.x;   // my point
  const int jb   = blockIdx.y * TPB;                 // my j-segment base

  __shared__ float sx[TPB], sy[TPB], sz[TPB];
  __shared__ float spx[TPB], spy[TPB], spz[TPB];

  {
    const int j = jb + threadIdx.x;
    sx[threadIdx.x]  = xpt[3 * j + 0];
    sy[threadIdx.x]  = xpt[3 * j + 1];
    sz[threadIdx.x]  = xpt[3 * j + 2];
    spx[threadIdx.x] = mom[3 * j + 0];
    spy[threadIdx.x] = mom[3 * j + 1];
    spz[threadIdx.x] = mom[3 * j + 2];
  }
  __syncthreads();

  const float xi = xpt[3 * i + 0], yi = xpt[3 * i + 1], zi = xpt[3 * i + 2];
  const float pxi = mom[3 * i + 0], pyi = mom[3 * i + 1], pzi = mom[3 * i + 2];

  float a = 0.f;                         // sum_j w_ij
  float wx = 0.f, wy = 0.f, wz = 0.f;    // sum_j w_ij * x_j
  float gx = 0.f, gy = 0.f, gz = 0.f;    // sum_j K_ij * p_j

#pragma unroll 8
  for (int j = 0; j < TPB; ++j) {
    const float bx = sx[j], by = sy[j], bz = sz[j];
    const float qx = spx[j], qy = spy[j], qz = spz[j];
    const float dx = xi - bx, dy = yi - by, dz = zi - bz;
    const float d2 = dx * dx + dy * dy + dz * dz;
    const float K = __expf(-GAMMA_F * d2);           // v_mul + v_exp_f32
    const float dot = pxi * qx + pyi * qy + pzi * qz;
    const float w = K * dot;
    a  += w;
    wx += w * bx; wy += w * by; wz += w * bz;
    gx += K * qx; gy += K * qy; gz += K * qz;
  }

  // dmom partial: 2*GAMMA*(x_i * a - wvec); linear in (a, wvec) so partials add.
  const float c = 2.0f * GAMMA_F;
  atomicAdd(&out[3 * i + 0], c * (xi * a - wx));
  atomicAdd(&out[3 * i + 1], c * (yi * a - wy));
  atomicAdd(&out[3 * i + 2], c * (zi * a - wz));
  atomicAdd(&out[3 * N + 3 * i + 0], gx);
  atomicAdd(&out[3 * N + 3 * i + 1], gy);
  atomicAdd(&out[3 * N + 3 * i + 2], gz);
}

extern "C" void kernel_launch(void* const* d_in, const int* in_sizes, int n_in,
                              void* d_out, int out_size, void* d_ws, size_t ws_size,
                              hipStream_t stream) {
  const float* mom = (const float*)d_in[0];           // setup_inputs order: mom first
  const float* xpt = (const float*)d_in[1];           // then control_points
  float* out = (float*)d_out;
  const int N = in_sizes[0] / 3;                      // 8192

  // d_out is poisoned to 0xAA before every timed call — zero it (memset node
  // is graph-capturable; ordering on `stream` guarantees it precedes atomics).
  hipMemsetAsync(d_out, 0, (size_t)out_size * sizeof(float), stream);

  dim3 grid(N / TPB, N / TPB);                        // 32 x 32 = 1024 blocks
  lddmm_evolve_kernel<<<grid, TPB, 0, stream>>>(mom, xpt, out, N);
}